// Round 1
// baseline (542.327 us; speedup 1.0000x reference)
//
#include <hip/hip_runtime.h>

#define IN_F 128
#define OUT_F 64

// h = node_feat @ W_node + b_node   [N, 64]
// 4 nodes per 256-thread block; 64 lanes per node, one output feature each.
__global__ void node_linear(const float* __restrict__ nf, const float* __restrict__ W,
                            const float* __restrict__ b, float* __restrict__ h, int n_nodes) {
    __shared__ float Wl[IN_F][OUT_F];   // 32 KB
    __shared__ float rows[4][IN_F];     // 2 KB
    const int tid = threadIdx.x;

    // Load W (8192 floats) as float4, coalesced.
    for (int i = tid; i < IN_F * OUT_F / 4; i += 256)
        ((float4*)Wl)[i] = ((const float4*)W)[i];

    const int base = blockIdx.x * 4;
    // Load up to 4 node rows (512 floats) as float4.
    for (int i = tid; i < 4 * IN_F / 4; i += 256) {
        int r = i / (IN_F / 4);
        int c = i % (IN_F / 4);
        if (base + r < n_nodes)
            ((float4*)rows[r])[c] = ((const float4*)(nf + (size_t)(base + r) * IN_F))[c];
    }
    __syncthreads();

    const int local = tid >> 6;      // which of the 4 nodes (== wave id)
    const int o     = tid & 63;      // output feature
    const int node  = base + local;
    if (node >= n_nodes) return;

    float acc = b[o];
#pragma unroll
    for (int k = 0; k < IN_F; ++k)
        acc = fmaf(rows[local][k], Wl[k][o], acc);   // rows: wave-broadcast; Wl: 2-way (free)

    h[(size_t)node * OUT_F + o] = acc;
}

// One 64-lane group per edge: m = h[src[e]] + (ef[e]*We + be); atomicAdd into out[dst[e]].
__global__ void edge_scatter(const float* __restrict__ ef, const float* __restrict__ We,
                             const float* __restrict__ be, const float* __restrict__ h,
                             const int* __restrict__ src, const int* __restrict__ dst,
                             float* __restrict__ out, float* __restrict__ deg, int n_edges) {
    long long idx = (long long)blockIdx.x * blockDim.x + threadIdx.x;
    int e = (int)(idx >> 6);
    int o = (int)(idx & 63);
    if (e >= n_edges) return;

    int s = src[e];
    int d = dst[e];
    float x = ef[e];
    float m = h[(size_t)s * OUT_F + o] + fmaf(x, We[o], be[o]);
    atomicAdd(out + (size_t)d * OUT_F + o, m);
    if (o == 0) atomicAdd(deg + d, 1.0f);
}

// out[n][o] /= max(deg[n], 1)
__global__ void finalize(float* __restrict__ out, const float* __restrict__ deg, int n_nodes) {
    int idx = blockIdx.x * blockDim.x + threadIdx.x;
    if (idx >= n_nodes * OUT_F) return;
    int n = idx >> 6;
    out[idx] = out[idx] / fmaxf(deg[n], 1.0f);
}

extern "C" void kernel_launch(void* const* d_in, const int* in_sizes, int n_in,
                              void* d_out, int out_size, void* d_ws, size_t ws_size,
                              hipStream_t stream) {
    const float* nf  = (const float*)d_in[0];   // node_feat [N,128]
    const float* ef  = (const float*)d_in[1];   // edge_feat [E,1]
    const float* Wn  = (const float*)d_in[2];   // W_node [128,64]
    const float* bn  = (const float*)d_in[3];   // b_node [64]
    const float* We  = (const float*)d_in[4];   // W_edge [1,64]
    const float* be  = (const float*)d_in[5];   // b_edge [64]
    const int*   src = (const int*)d_in[6];     // [E]
    const int*   dst = (const int*)d_in[7];     // [E]
    float* out = (float*)d_out;                 // [N,64]

    const int n_nodes = in_sizes[0] / IN_F;
    const int n_edges = in_sizes[6];

    float* h   = (float*)d_ws;                          // [N,64]
    float* deg = h + (size_t)n_nodes * OUT_F;           // [N]

    hipMemsetAsync(out, 0, (size_t)n_nodes * OUT_F * sizeof(float), stream);
    hipMemsetAsync(deg, 0, (size_t)n_nodes * sizeof(float), stream);

    node_linear<<<(n_nodes + 3) / 4, 256, 0, stream>>>(nf, Wn, bn, h, n_nodes);

    long long tot = (long long)n_edges * 64;
    edge_scatter<<<(int)((tot + 255) / 256), 256, 0, stream>>>(ef, We, be, h, src, dst, out, deg, n_edges);

    finalize<<<(int)(((long long)n_nodes * OUT_F + 255) / 256), 256, 0, stream>>>(out, deg, n_nodes);
}

// Round 2
// 398.991 us; speedup vs baseline: 1.3592x; 1.3592x over previous
//
#include <hip/hip_runtime.h>

#define IN_F 128
#define OUT_F 64

// ---------------- node linear: h = nf @ W + b, 64x64 tile, reg-blocked 4x4 ----------------
__global__ __launch_bounds__(256) void node_linear(const float* __restrict__ nf,
                                                   const float* __restrict__ W,
                                                   const float* __restrict__ b,
                                                   float* __restrict__ h, int n_nodes) {
    __shared__ float Wl[IN_F][OUT_F];   // 32 KB, row k: W[k][0..63]
    __shared__ float rT[IN_F][64];      // 32 KB, transposed rows, XOR-swizzled columns
    const int tid = threadIdx.x;

    // Load W (2048 float4s), coalesced, conflict-free b128 writes.
    for (int i = tid; i < IN_F * OUT_F / 4; i += 256) {
        float4 v = ((const float4*)W)[i];
        *(float4*)&Wl[i >> 4][(i & 15) << 2] = v;
    }

    const int t0 = blockIdx.x * 64;
    // Load 64 node rows (coalesced float4) and transpose into rT with XOR swizzle:
    // value (node r, feat k) stored at rT[k][ r ^ ((k>>2 & 15)<<2) ].
    for (int i = tid; i < 64 * IN_F / 4; i += 256) {
        int r = i >> 5, k4 = i & 31;
        int node = t0 + r;
        float4 v = make_float4(0.f, 0.f, 0.f, 0.f);
        if (node < n_nodes) v = ((const float4*)(nf + (size_t)node * IN_F))[k4];
        int col = r ^ ((k4 & 15) << 2);
        rT[k4 * 4 + 0][col] = v.x;
        rT[k4 * 4 + 1][col] = v.y;
        rT[k4 * 4 + 2][col] = v.z;
        rT[k4 * 4 + 3][col] = v.w;
    }
    __syncthreads();

    const int nr = tid >> 4;   // node group 0..15 (4 nodes each)
    const int oc = tid & 15;   // out group 0..15  (4 outs each)
    float4 bb = ((const float4*)b)[oc];
    float4 a0 = bb, a1 = bb, a2 = bb, a3 = bb;   // a_i = node nr*4+i, comps = outs oc*4..+3

#pragma unroll 16
    for (int k = 0; k < IN_F; ++k) {
        float4 wv = *(const float4*)&Wl[k][oc << 2];
        int col = (nr << 2) ^ (((k >> 2) & 15) << 2);
        float4 rv = *(const float4*)&rT[k][col];
        a0.x = fmaf(rv.x, wv.x, a0.x); a0.y = fmaf(rv.x, wv.y, a0.y);
        a0.z = fmaf(rv.x, wv.z, a0.z); a0.w = fmaf(rv.x, wv.w, a0.w);
        a1.x = fmaf(rv.y, wv.x, a1.x); a1.y = fmaf(rv.y, wv.y, a1.y);
        a1.z = fmaf(rv.y, wv.z, a1.z); a1.w = fmaf(rv.y, wv.w, a1.w);
        a2.x = fmaf(rv.z, wv.x, a2.x); a2.y = fmaf(rv.z, wv.y, a2.y);
        a2.z = fmaf(rv.z, wv.z, a2.z); a2.w = fmaf(rv.z, wv.w, a2.w);
        a3.x = fmaf(rv.w, wv.x, a3.x); a3.y = fmaf(rv.w, wv.y, a3.y);
        a3.z = fmaf(rv.w, wv.z, a3.z); a3.w = fmaf(rv.w, wv.w, a3.w);
    }

    float4 accs[4] = {a0, a1, a2, a3};
#pragma unroll
    for (int i = 0; i < 4; ++i) {
        int node = t0 + nr * 4 + i;
        if (node < n_nodes)
            *(float4*)&h[(size_t)node * OUT_F + (oc << 2)] = accs[i];
    }
}

// ---------------- degree histogram ----------------
__global__ void hist(const int* __restrict__ dst, int* __restrict__ deg, int n_edges) {
    for (int e = blockIdx.x * blockDim.x + threadIdx.x; e < n_edges; e += gridDim.x * blockDim.x)
        atomicAdd(&deg[dst[e]], 1);
}

// ---------------- exclusive scan over deg -> offs (3 kernels, chunk=512) ----------------
__global__ void scan_a(const int* __restrict__ deg, int* __restrict__ bsum, int n) {
    __shared__ int s[256];
    int tid = threadIdx.x;
    int g = blockIdx.x * 512 + tid;
    int v = (g < n ? deg[g] : 0) + (g + 256 < n ? deg[g + 256] : 0);
    s[tid] = v;
    __syncthreads();
    for (int off = 128; off > 0; off >>= 1) {
        if (tid < off) s[tid] += s[tid + off];
        __syncthreads();
    }
    if (tid == 0) bsum[blockIdx.x] = s[0];
}

__global__ void scan_b(const int* __restrict__ bsum, int* __restrict__ bscan, int nblk) {
    __shared__ int s[256];
    int i = threadIdx.x;
    int v = (i < nblk) ? bsum[i] : 0;
    s[i] = v;
    __syncthreads();
    for (int off = 1; off < 256; off <<= 1) {
        int t = (i >= off) ? s[i - off] : 0;
        __syncthreads();
        s[i] += t;
        __syncthreads();
    }
    if (i < nblk) bscan[i] = s[i] - v;   // exclusive
}

__global__ void scan_c(const int* __restrict__ deg, const int* __restrict__ bscan,
                       int* __restrict__ offs, int* __restrict__ cursor, int n) {
    __shared__ int s[512];
    int i = threadIdx.x;
    int g = blockIdx.x * 512 + i;
    int v = (g < n) ? deg[g] : 0;
    s[i] = v;
    __syncthreads();
    for (int off = 1; off < 512; off <<= 1) {
        int t = (i >= off) ? s[i - off] : 0;
        __syncthreads();
        s[i] += t;
        __syncthreads();
    }
    int o = bscan[blockIdx.x] + s[i] - v;
    if (g < n) { offs[g] = o; cursor[g] = o; }
}

// ---------------- bucket-place edges: es[pos] = (src, edge_feat) ----------------
__global__ void scatter_edges(const int* __restrict__ src, const int* __restrict__ dst,
                              const float* __restrict__ ef, int* __restrict__ cursor,
                              int2* __restrict__ es, int n_edges) {
    for (int e = blockIdx.x * blockDim.x + threadIdx.x; e < n_edges; e += gridDim.x * blockDim.x) {
        int d = dst[e];
        int pos = atomicAdd(&cursor[d], 1);
        es[pos] = make_int2(src[e], __float_as_int(ef[e]));
    }
}

// ---------------- per-node gather + mean ----------------
// One 64-lane wave per node; lane = output feature.
// sum_e [h[src_e] + x_e*We + be] = sum_e h[src_e] + We*sum(x_e) + deg*be
__global__ __launch_bounds__(256) void aggregate(const float* __restrict__ h,
                                                 const int2* __restrict__ es,
                                                 const int* __restrict__ offs,
                                                 const int* __restrict__ deg,
                                                 const float* __restrict__ We,
                                                 const float* __restrict__ be,
                                                 float* __restrict__ out, int n_nodes) {
    int node = blockIdx.x * 4 + (threadIdx.x >> 6);
    int o = threadIdx.x & 63;
    if (node >= n_nodes) return;
    int start = offs[node];
    int dg = deg[node];
    float acc = 0.f, sx = 0.f;
    for (int j = start; j < start + dg; ++j) {
        int2 e = es[j];
        acc += h[(size_t)e.x * OUT_F + o];
        sx += __int_as_float(e.y);
    }
    float r = 0.f;
    if (dg > 0) r = (acc + We[o] * sx + (float)dg * be[o]) / (float)dg;
    out[(size_t)node * OUT_F + o] = r;
}

extern "C" void kernel_launch(void* const* d_in, const int* in_sizes, int n_in,
                              void* d_out, int out_size, void* d_ws, size_t ws_size,
                              hipStream_t stream) {
    const float* nf  = (const float*)d_in[0];
    const float* ef  = (const float*)d_in[1];
    const float* Wn  = (const float*)d_in[2];
    const float* bn  = (const float*)d_in[3];
    const float* We  = (const float*)d_in[4];
    const float* be  = (const float*)d_in[5];
    const int*   src = (const int*)d_in[6];
    const int*   dst = (const int*)d_in[7];
    float* out = (float*)d_out;

    const int n_nodes = in_sizes[0] / IN_F;
    const int n_edges = in_sizes[6];

    char* w = (char*)d_ws;
    float* h    = (float*)w; w += (size_t)n_nodes * OUT_F * sizeof(float);   // 25.6 MB
    int2*  es   = (int2*)w;  w += (size_t)n_edges * sizeof(int2);            // 12.8 MB
    int* deg_i  = (int*)w;   w += (size_t)n_nodes * sizeof(int);
    int* offs   = (int*)w;   w += (size_t)n_nodes * sizeof(int);
    int* cursor = (int*)w;   w += (size_t)n_nodes * sizeof(int);
    int* bsum   = (int*)w;   w += 4096;
    int* bscan  = (int*)w;

    const int nblk = (n_nodes + 511) / 512;   // 196 (must be <= 256)

    hipMemsetAsync(deg_i, 0, (size_t)n_nodes * sizeof(int), stream);

    node_linear<<<(n_nodes + 63) / 64, 256, 0, stream>>>(nf, Wn, bn, h, n_nodes);
    hist<<<2048, 256, 0, stream>>>(dst, deg_i, n_edges);
    scan_a<<<nblk, 256, 0, stream>>>(deg_i, bsum, n_nodes);
    scan_b<<<1, 256, 0, stream>>>(bsum, bscan, nblk);
    scan_c<<<nblk, 512, 0, stream>>>(deg_i, bscan, offs, cursor, n_nodes);
    scatter_edges<<<2048, 256, 0, stream>>>(src, dst, ef, cursor, es, n_edges);
    aggregate<<<(n_nodes + 3) / 4, 256, 0, stream>>>(h, es, offs, deg_i, We, be, out, n_nodes);
}

// Round 3
// 328.997 us; speedup vs baseline: 1.6484x; 1.2128x over previous
//
#include <hip/hip_runtime.h>

#define IN_F 128
#define OUT_F 64

static __device__ __forceinline__ unsigned short f2bf(float f) {
    unsigned u = __float_as_uint(f);
    u += 0x7FFF + ((u >> 16) & 1);    // round-to-nearest-even
    return (unsigned short)(u >> 16);
}
static __device__ __forceinline__ float bf2f(unsigned short h) {
    return __uint_as_float(((unsigned)h) << 16);
}

// ---------------- node linear: h16 = bf16(nf @ W + b), 64x64 tile, reg-blocked 4x4 ----------------
__global__ __launch_bounds__(256) void node_linear(const float* __restrict__ nf,
                                                   const float* __restrict__ W,
                                                   const float* __restrict__ b,
                                                   unsigned short* __restrict__ h16, int n_nodes) {
    __shared__ float Wl[IN_F][OUT_F];   // 32 KB
    __shared__ float rT[IN_F][64];      // 32 KB, transposed rows, XOR-swizzled columns
    const int tid = threadIdx.x;

    for (int i = tid; i < IN_F * OUT_F / 4; i += 256) {
        float4 v = ((const float4*)W)[i];
        *(float4*)&Wl[i >> 4][(i & 15) << 2] = v;
    }

    const int t0 = blockIdx.x * 64;
    for (int i = tid; i < 64 * IN_F / 4; i += 256) {
        int r = i >> 5, k4 = i & 31;
        int node = t0 + r;
        float4 v = make_float4(0.f, 0.f, 0.f, 0.f);
        if (node < n_nodes) v = ((const float4*)(nf + (size_t)node * IN_F))[k4];
        int col = r ^ ((k4 & 15) << 2);
        rT[k4 * 4 + 0][col] = v.x;
        rT[k4 * 4 + 1][col] = v.y;
        rT[k4 * 4 + 2][col] = v.z;
        rT[k4 * 4 + 3][col] = v.w;
    }
    __syncthreads();

    const int nr = tid >> 4;   // node group 0..15 (4 nodes each)
    const int oc = tid & 15;   // out group 0..15  (4 outs each)
    float4 bb = ((const float4*)b)[oc];
    float4 a0 = bb, a1 = bb, a2 = bb, a3 = bb;

#pragma unroll 16
    for (int k = 0; k < IN_F; ++k) {
        float4 wv = *(const float4*)&Wl[k][oc << 2];
        int col = (nr << 2) ^ (((k >> 2) & 15) << 2);
        float4 rv = *(const float4*)&rT[k][col];
        a0.x = fmaf(rv.x, wv.x, a0.x); a0.y = fmaf(rv.x, wv.y, a0.y);
        a0.z = fmaf(rv.x, wv.z, a0.z); a0.w = fmaf(rv.x, wv.w, a0.w);
        a1.x = fmaf(rv.y, wv.x, a1.x); a1.y = fmaf(rv.y, wv.y, a1.y);
        a1.z = fmaf(rv.y, wv.z, a1.z); a1.w = fmaf(rv.y, wv.w, a1.w);
        a2.x = fmaf(rv.z, wv.x, a2.x); a2.y = fmaf(rv.z, wv.y, a2.y);
        a2.z = fmaf(rv.z, wv.z, a2.z); a2.w = fmaf(rv.z, wv.w, a2.w);
        a3.x = fmaf(rv.w, wv.x, a3.x); a3.y = fmaf(rv.w, wv.y, a3.y);
        a3.z = fmaf(rv.w, wv.z, a3.z); a3.w = fmaf(rv.w, wv.w, a3.w);
    }

    float4 accs[4] = {a0, a1, a2, a3};
#pragma unroll
    for (int i = 0; i < 4; ++i) {
        int node = t0 + nr * 4 + i;
        if (node < n_nodes) {
            ushort4 pv;
            pv.x = f2bf(accs[i].x); pv.y = f2bf(accs[i].y);
            pv.z = f2bf(accs[i].z); pv.w = f2bf(accs[i].w);
            *(ushort4*)&h16[(size_t)node * OUT_F + (oc << 2)] = pv;
        }
    }
}

// ---------------- degree histogram (x4 unrolled) ----------------
__global__ void hist(const int* __restrict__ dst, int* __restrict__ deg, int n_edges) {
    int t = blockIdx.x * blockDim.x + threadIdx.x;
    int base = t * 4;
    if (base + 4 <= n_edges) {
        int4 d = *(const int4*)(dst + base);
        atomicAdd(&deg[d.x], 1);
        atomicAdd(&deg[d.y], 1);
        atomicAdd(&deg[d.z], 1);
        atomicAdd(&deg[d.w], 1);
    } else {
        for (int e = base; e < n_edges; ++e) atomicAdd(&deg[dst[e]], 1);
    }
}

// ---------------- exclusive scan over deg -> offs ----------------
__global__ void scan_a(const int* __restrict__ deg, int* __restrict__ bsum, int n) {
    __shared__ int s[256];
    int tid = threadIdx.x;
    int g = blockIdx.x * 512 + tid;
    int v = (g < n ? deg[g] : 0) + (g + 256 < n ? deg[g + 256] : 0);
    s[tid] = v;
    __syncthreads();
    for (int off = 128; off > 0; off >>= 1) {
        if (tid < off) s[tid] += s[tid + off];
        __syncthreads();
    }
    if (tid == 0) bsum[blockIdx.x] = s[0];
}

__global__ void scan_b(const int* __restrict__ bsum, int* __restrict__ bscan, int nblk) {
    __shared__ int s[256];
    int i = threadIdx.x;
    int v = (i < nblk) ? bsum[i] : 0;
    s[i] = v;
    __syncthreads();
    for (int off = 1; off < 256; off <<= 1) {
        int t = (i >= off) ? s[i - off] : 0;
        __syncthreads();
        s[i] += t;
        __syncthreads();
    }
    if (i < nblk) bscan[i] = s[i] - v;   // exclusive
}

__global__ void scan_c(const int* __restrict__ deg, const int* __restrict__ bscan,
                       int* __restrict__ offs, int* __restrict__ cursor, int n) {
    __shared__ int s[512];
    int i = threadIdx.x;
    int g = blockIdx.x * 512 + i;
    int v = (g < n) ? deg[g] : 0;
    s[i] = v;
    __syncthreads();
    for (int off = 1; off < 512; off <<= 1) {
        int t = (i >= off) ? s[i - off] : 0;
        __syncthreads();
        s[i] += t;
        __syncthreads();
    }
    int o = bscan[blockIdx.x] + s[i] - v;
    if (g < n) { offs[g] = o; cursor[g] = o; }
}

// ---------------- bucket-place edges (x4 unrolled): es[pos] = (src, ef) ----------------
__global__ void scatter_edges(const int* __restrict__ src, const int* __restrict__ dst,
                              const float* __restrict__ ef, int* __restrict__ cursor,
                              int2* __restrict__ es, int n_edges) {
    int t = blockIdx.x * blockDim.x + threadIdx.x;
    int base = t * 4;
    if (base + 4 <= n_edges) {
        int4 s4 = *(const int4*)(src + base);
        int4 d4 = *(const int4*)(dst + base);
        float4 x4 = *(const float4*)(ef + base);
        int p0 = atomicAdd(&cursor[d4.x], 1);
        int p1 = atomicAdd(&cursor[d4.y], 1);
        int p2 = atomicAdd(&cursor[d4.z], 1);
        int p3 = atomicAdd(&cursor[d4.w], 1);
        es[p0] = make_int2(s4.x, __float_as_int(x4.x));
        es[p1] = make_int2(s4.y, __float_as_int(x4.y));
        es[p2] = make_int2(s4.z, __float_as_int(x4.z));
        es[p3] = make_int2(s4.w, __float_as_int(x4.w));
    } else {
        for (int e = base; e < n_edges; ++e) {
            int pos = atomicAdd(&cursor[dst[e]], 1);
            es[pos] = make_int2(src[e], __float_as_int(ef[e]));
        }
    }
}

// ---------------- per-node gather + mean, 8 gathers in flight ----------------
__global__ __launch_bounds__(256) void aggregate(const unsigned short* __restrict__ h16,
                                                 const int2* __restrict__ es,
                                                 const int* __restrict__ offs,
                                                 const int* __restrict__ deg,
                                                 const float* __restrict__ We,
                                                 const float* __restrict__ be,
                                                 float* __restrict__ out, int n_nodes) {
    int node = blockIdx.x * 4 + (threadIdx.x >> 6);
    int o = threadIdx.x & 63;
    if (node >= n_nodes) return;
    int start = offs[node];
    int dg = deg[node];
    const int2* ep = es + start;

    float acc[8] = {0.f, 0.f, 0.f, 0.f, 0.f, 0.f, 0.f, 0.f};
    float sx = 0.f;
    int j = 0;
    for (; j + 8 <= dg; j += 8) {
        int2 e[8];
#pragma unroll
        for (int u = 0; u < 8; ++u) e[u] = ep[j + u];
        unsigned short hv[8];
#pragma unroll
        for (int u = 0; u < 8; ++u) hv[u] = h16[(size_t)e[u].x * OUT_F + o];
#pragma unroll
        for (int u = 0; u < 8; ++u) {
            acc[u] += bf2f(hv[u]);
            sx += __int_as_float(e[u].y);
        }
    }
    for (; j < dg; ++j) {
        int2 e = ep[j];
        acc[0] += bf2f(h16[(size_t)e.x * OUT_F + o]);
        sx += __int_as_float(e.y);
    }
    float a = ((acc[0] + acc[1]) + (acc[2] + acc[3])) + ((acc[4] + acc[5]) + (acc[6] + acc[7]));
    float r = 0.f;
    if (dg > 0) r = (a + We[o] * sx + (float)dg * be[o]) / (float)dg;
    out[(size_t)node * OUT_F + o] = r;
}

extern "C" void kernel_launch(void* const* d_in, const int* in_sizes, int n_in,
                              void* d_out, int out_size, void* d_ws, size_t ws_size,
                              hipStream_t stream) {
    const float* nf  = (const float*)d_in[0];
    const float* ef  = (const float*)d_in[1];
    const float* Wn  = (const float*)d_in[2];
    const float* bn  = (const float*)d_in[3];
    const float* We  = (const float*)d_in[4];
    const float* be  = (const float*)d_in[5];
    const int*   src = (const int*)d_in[6];
    const int*   dst = (const int*)d_in[7];
    float* out = (float*)d_out;

    const int n_nodes = in_sizes[0] / IN_F;
    const int n_edges = in_sizes[6];

    char* w = (char*)d_ws;
    unsigned short* h16 = (unsigned short*)w; w += (size_t)n_nodes * OUT_F * sizeof(unsigned short); // 12.8 MB
    int2* es    = (int2*)w;  w += (size_t)n_edges * sizeof(int2);            // 12.8 MB
    int* deg_i  = (int*)w;   w += (size_t)n_nodes * sizeof(int);
    int* offs   = (int*)w;   w += (size_t)n_nodes * sizeof(int);
    int* cursor = (int*)w;   w += (size_t)n_nodes * sizeof(int);
    int* bsum   = (int*)w;   w += 4096;
    int* bscan  = (int*)w;

    const int nblk = (n_nodes + 511) / 512;   // 196 (<= 256)

    hipMemsetAsync(deg_i, 0, (size_t)n_nodes * sizeof(int), stream);

    hist<<<(n_edges / 4 + 255) / 256 + 1, 256, 0, stream>>>(dst, deg_i, n_edges);
    node_linear<<<(n_nodes + 63) / 64, 256, 0, stream>>>(nf, Wn, bn, h16, n_nodes);
    scan_a<<<nblk, 256, 0, stream>>>(deg_i, bsum, n_nodes);
    scan_b<<<1, 256, 0, stream>>>(bsum, bscan, nblk);
    scan_c<<<nblk, 512, 0, stream>>>(deg_i, bscan, offs, cursor, n_nodes);
    scatter_edges<<<(n_edges / 4 + 255) / 256 + 1, 256, 0, stream>>>(src, dst, ef, cursor, es, n_edges);
    aggregate<<<(n_nodes + 3) / 4, 256, 0, stream>>>(h16, es, offs, deg_i, We, be, out, n_nodes);
}